// Round 7
// baseline (51.078 us; speedup 1.0000x reference)
//
#include <hip/hip_runtime.h>

// NgramMinPooling: B=32, S=2048, H=512, N_GRAM=3, float32.
// Row r selected (r in sorted+unique rand_index):
//   m = min(x[r], x[r-1], x[r-2])  (within batch; rows shifted past the
//   batch start contribute 0 -- reference zero-pads)
// else m = x[r].
// out = sigmoid(x)*m + (1-sigmoid(x))*x
//
// SINGLE fused kernel, BARRIER-FREE membership (round-6 post-mortem: the
// two __syncthreads of the block-level search re-serialized the 16 waves
// and cost more than the saved launch):
//  - 1024 threads = 8 rows/block, one float4 per thread per row
//  - bulk row loads issued first (v1/v2 unconditional: same-block rows are
//    L1 hits; selection only gates the final select)
//  - per-wave 3-round 64-ary search of sorted idx (each wave is entirely
//    within one row, so the target is wave-uniform):
//      L1: 64 probes at stride s1=ceil(n/64)=717, ballot -> 718-window
//      L2: 64 probes at stride s2=12,            ballot -> 13-window
//      L3: 13-lane equality probe,               ballot != 0 -> selected
//    Dependent-load depth 3, no LDS, no barriers. L1-probe lines are
//    identical for every wave on the chip -> L1-cache resident.
//  - XCD-contiguous block swizzle: boundary neighbor reads hit same-XCD L2
//  - nontemporal stores: out is write-once, keep it out of L2

#define S_LEN 2048
#define H_LEN 512
#define ROWS_PER_BLOCK 8
#define NTHREADS 1024

typedef float f32x4 __attribute__((ext_vector_type(4)));

__global__ __launch_bounds__(NTHREADS)
void ngram_min_pool(const float* __restrict__ x,
                    const int* __restrict__ idx,
                    int n_idx,
                    float* __restrict__ out,
                    int nwg)
{
    // XCD-contiguous swizzle: XCD j owns blocks [j*nwg/8, (j+1)*nwg/8)
    int bid = blockIdx.x;
    const int cpx = nwg >> 3;               // nwg % 8 == 0 (8192)
    bid = (bid & 7) * cpx + (bid >> 3);

    const int tid  = threadIdx.x;
    const int rowg = tid >> 7;              // which of the 8 rows
    const int row  = bid * ROWS_PER_BLOCK + rowg;
    const int lane = tid & 127;             // float4 slot within the row
    const int s    = row & (S_LEN - 1);     // position within sequence

    // ---- bulk loads first: 16 KB/block, hides the search latency ----
    const size_t base = (size_t)row * H_LEN;
    const f32x4 v0 = reinterpret_cast<const f32x4*>(x + base)[lane];
    f32x4 v1 = (f32x4)(0.f);
    f32x4 v2 = (f32x4)(0.f);
    if (s >= 1) v1 = reinterpret_cast<const f32x4*>(x + base - H_LEN)[lane];
    if (s >= 2) v2 = reinterpret_cast<const f32x4*>(x + base - 2 * H_LEN)[lane];

    // ---- per-wave 64-ary membership search (no barriers, no LDS) ----
    const int wl = tid & 63;                 // lane within wave
    const int s1 = (n_idx + 63) >> 6;        // 717
    int p = wl * s1;
    bool pred = (p < n_idx) && (idx[p] < row);
    int k = __popcll(__ballot(pred));
    const int w0 = (k == 0) ? 0 : (k - 1) * s1;   // match pos in [w0, w0+s1]

    const int s2 = (s1 + 64) >> 6;           // 12 = ceil((s1+1)/64)
    p = w0 + wl * s2;
    pred = (p < n_idx) && (idx[p] < row);
    k = __popcll(__ballot(pred));
    const int w1 = (k == 0) ? w0 : w0 + (k - 1) * s2; // pos in [w1, w1+s2]

    p = w1 + wl;
    pred = (wl <= s2) && (p < n_idx) && (idx[p] == row);
    const bool selected = __ballot(pred) != 0ull;    // wave-uniform

    // ---- min + select + sigmoid blend ----
    f32x4 m;
    m.x = fminf(v0.x, fminf(v1.x, v2.x));
    m.y = fminf(v0.y, fminf(v1.y, v2.y));
    m.z = fminf(v0.z, fminf(v1.z, v2.z));
    m.w = fminf(v0.w, fminf(v1.w, v2.w));
    if (!selected) m = v0;

    f32x4 r;
    const float gx = 1.0f / (1.0f + __expf(-v0.x));
    const float gy = 1.0f / (1.0f + __expf(-v0.y));
    const float gz = 1.0f / (1.0f + __expf(-v0.z));
    const float gw = 1.0f / (1.0f + __expf(-v0.w));
    r.x = gx * m.x + (1.0f - gx) * v0.x;
    r.y = gy * m.y + (1.0f - gy) * v0.y;
    r.z = gz * m.z + (1.0f - gz) * v0.z;
    r.w = gw * m.w + (1.0f - gw) * v0.w;

    __builtin_nontemporal_store(r, reinterpret_cast<f32x4*>(out + base) + lane);
}

extern "C" void kernel_launch(void* const* d_in, const int* in_sizes, int n_in,
                              void* d_out, int out_size, void* d_ws, size_t ws_size,
                              hipStream_t stream)
{
    const float* x   = (const float*)d_in[0];
    const int*   idx = (const int*)d_in[1];
    const int n_idx  = in_sizes[1];
    float* out = (float*)d_out;

    const int n_rows = in_sizes[0] / H_LEN;   // B*S = 65536
    const int nwg = n_rows / ROWS_PER_BLOCK;  // 8192
    ngram_min_pool<<<nwg, NTHREADS, 0, stream>>>(x, idx, n_idx, out, nwg);
}

// Round 8
// 47.251 us; speedup vs baseline: 1.0810x; 1.0810x over previous
//
#include <hip/hip_runtime.h>

// NgramMinPooling: B=32, S=2048, H=512, N_GRAM=3, float32.
// Row r selected (r in sorted+unique rand_index):
//   m = min(x[r], x[r-1], x[r-2])  (within batch; rows shifted past the
//   batch start contribute 0)
// else m = x[r].
// out = sigmoid(x)*m + (1-sigmoid(x))*x
//
// ROUND-5 CHAMPION STRUCTURE (47.2 us; rounds 6/7 fused-search variants
// regressed to 48.5/51.1 us -- per-wave membership search costs more than
// one tiny scatter dispatch):
//  (1) build_flags: idx is sorted+unique, thread i sets flags[idx[i]]=1 and
//      zeros the gap to idx[i+1] (mean gap 1.43). One launch, no memset.
//  (2) main near-copy kernel at HBM BW:
//      - 1024 threads = 8 rows/block -> neighbor-row reads are L1 hits
//        except at block boundaries
//      - XCD-contiguous block swizzle so boundary reads hit same-XCD L2
//      - nontemporal stores (clang ext_vector type): out is write-once

#define S_LEN 2048
#define H_LEN 512
#define ROWS_PER_BLOCK 8          // 1024 threads, 128 per row (one float4 each)

typedef float f32x4 __attribute__((ext_vector_type(4)));

__global__ __launch_bounds__(256)
void build_flags(const int* __restrict__ idx, int n_idx, int n_rows,
                 unsigned char* __restrict__ flags)
{
    int i = blockIdx.x * 256 + threadIdx.x;
    if (i >= n_idx) return;
    const int cur = idx[i];
    flags[cur] = 1;
    const int next = (i + 1 < n_idx) ? idx[i + 1] : n_rows;
    for (int k = cur + 1; k < next; ++k) flags[k] = 0;
    if (i == 0)
        for (int k = 0; k < cur; ++k) flags[k] = 0;
}

__global__ __launch_bounds__(1024)
void ngram_min_pool(const float* __restrict__ x,
                    const unsigned char* __restrict__ flags,
                    float* __restrict__ out,
                    int nwg)
{
    // XCD-contiguous swizzle: XCD k owns blocks [k*nwg/8, (k+1)*nwg/8)
    int bid = blockIdx.x;
    const int cpx = nwg >> 3;               // nwg % 8 == 0 (8192)
    bid = (bid & 7) * cpx + (bid >> 3);

    const int tid  = threadIdx.x;
    const int row  = bid * ROWS_PER_BLOCK + (tid >> 7);
    const int lane = tid & 127;             // float4 slot within the row
    const int s    = row & (S_LEN - 1);     // position within sequence

    const bool selected = flags[row] != 0;

    const size_t base = (size_t)row * H_LEN;
    const f32x4 v0 = reinterpret_cast<const f32x4*>(x + base)[lane];
    f32x4 m = v0;

    if (selected) {
        f32x4 v1 = (f32x4)(0.f);
        f32x4 v2 = (f32x4)(0.f);
        if (s >= 1) v1 = reinterpret_cast<const f32x4*>(x + base - H_LEN)[lane];
        if (s >= 2) v2 = reinterpret_cast<const f32x4*>(x + base - 2 * H_LEN)[lane];
        m.x = fminf(v0.x, fminf(v1.x, v2.x));
        m.y = fminf(v0.y, fminf(v1.y, v2.y));
        m.z = fminf(v0.z, fminf(v1.z, v2.z));
        m.w = fminf(v0.w, fminf(v1.w, v2.w));
    }

    f32x4 r;
    const float gx = 1.0f / (1.0f + __expf(-v0.x));
    const float gy = 1.0f / (1.0f + __expf(-v0.y));
    const float gz = 1.0f / (1.0f + __expf(-v0.z));
    const float gw = 1.0f / (1.0f + __expf(-v0.w));
    r.x = gx * m.x + (1.0f - gx) * v0.x;
    r.y = gy * m.y + (1.0f - gy) * v0.y;
    r.z = gz * m.z + (1.0f - gz) * v0.z;
    r.w = gw * m.w + (1.0f - gw) * v0.w;

    __builtin_nontemporal_store(r, reinterpret_cast<f32x4*>(out + base) + lane);
}

extern "C" void kernel_launch(void* const* d_in, const int* in_sizes, int n_in,
                              void* d_out, int out_size, void* d_ws, size_t ws_size,
                              hipStream_t stream)
{
    const float* x   = (const float*)d_in[0];
    const int*   idx = (const int*)d_in[1];
    const int n_idx  = in_sizes[1];
    float* out = (float*)d_out;

    const int n_rows = in_sizes[0] / H_LEN;   // B*S = 65536
    unsigned char* flags = (unsigned char*)d_ws;

    build_flags<<<(n_idx + 255) / 256, 256, 0, stream>>>(idx, n_idx, n_rows, flags);

    const int nwg = n_rows / ROWS_PER_BLOCK;  // 8192
    ngram_min_pool<<<nwg, 1024, 0, stream>>>(x, flags, out, nwg);
}